// Round 7
// baseline (468.045 us; speedup 1.0000x reference)
//
#include <hip/hip_runtime.h>
#include <hip/hip_bf16.h>

#define DIM   1024
#define NVEC  128
#define BROWS 32768

typedef short s16x8 __attribute__((ext_vector_type(8)));
typedef float f32x4 __attribute__((ext_vector_type(4)));

__device__ __forceinline__ unsigned short f2bf(float f) {
    union { float f; unsigned int u; } c; c.f = f;
    unsigned int u = c.u;
    u += 0x7fffu + ((u >> 16) & 1u);   // round-to-nearest-even
    return (unsigned short)(u >> 16);
}

// async global->LDS, 16B per lane; LDS dest = wave-uniform base + lane*16
__device__ __forceinline__ void cp16(const void* g, void* l) {
    __builtin_amdgcn_global_load_lds(
        (const __attribute__((address_space(1))) unsigned int*)g,
        (__attribute__((address_space(3))) unsigned int*)l, 16, 0, 0);
}

// ---------------------------------------------------------------------------
// K1: per-column normalize v AND raw Gram row (rescale trick):
//   G[i][j] = <v_i_raw, v_j_raw> * rn_i * rn_j  (scaling applied in k_tinv)
// ---------------------------------------------------------------------------
__global__ __launch_bounds__(256) void k_normgram(const float* __restrict__ v,
                                                  float* __restrict__ VnT,
                                                  float* __restrict__ rn_out,
                                                  float* __restrict__ G0) {
    int i = blockIdx.x, t = threadIdx.x;
    __shared__ float col[DIM];
    __shared__ float red[4];
    __shared__ float part[256];
    float c4[4]; float ss = 0.f;
#pragma unroll
    for (int u = 0; u < 4; ++u) {
        int d = t + u * 256;
        float val = v[d * NVEC + i];
        c4[u] = val; col[d] = val; ss += val * val;
    }
#pragma unroll
    for (int o = 32; o > 0; o >>= 1) ss += __shfl_down(ss, o, 64);
    if ((t & 63) == 0) red[t >> 6] = ss;
    __syncthreads();
    float rn = rsqrtf(red[0] + red[1] + red[2] + red[3]);
    if (t == 0) rn_out[i] = rn;
#pragma unroll
    for (int u = 0; u < 4; ++u) {
        int d = t + u * 256;
        VnT[i * DIM + d] = c4[u] * rn;
    }
    // raw Gram row: thread t -> j = t&127, d-half = t>>7
    int j = t & 127, half = t >> 7;
    const float* vp = v + (size_t)(half * 512) * NVEC + j;
    float s = 0.f;
#pragma unroll 4
    for (int d = 0; d < 512; ++d)
        s += col[half * 512 + d] * vp[(size_t)d * NVEC];
    part[t] = s;
    __syncthreads();
    if (t < 128) G0[i * NVEC + t] = part[t] + part[t + 128];
}

// ---------------------------------------------------------------------------
// K2: T = R^{-1}, R = 0.5*I + strict_upper(G), G = G0 * rn_i * rn_j
// ---------------------------------------------------------------------------
__global__ __launch_bounds__(256) void k_tinv(const float* __restrict__ G0,
                                              const float* __restrict__ rn,
                                              float* __restrict__ Tout) {
    __shared__ __align__(16) float Ts[NVEC * NVEC];   // 65536 B
    __shared__ float rs[NVEC];
    int t = threadIdx.x;
    if (t < NVEC) rs[t] = rn[t];
    __syncthreads();

    {   // phase 0: R into LDS (0.5 on diag, zeros below), rn rescale folded
        int i = t >> 1, jb = (t & 1) * 64;
        float rni = rs[i];
        for (int j = jb; j < jb + 64; j++) {
            float val = 0.f;
            if (j > i)       val = G0[i * NVEC + j] * rni * rs[j];
            else if (j == i) val = 0.5f;
            Ts[i * NVEC + j] = val;
        }
    }
    __syncthreads();

    {   // phase 1: invert 8 diagonal 16x16 blocks
        int blk = t >> 4, c = t & 15, rb = blk * 16;
        float xs[16];
        if (t < 128) {
#pragma unroll
            for (int jj = 0; jj < 16; jj++) xs[jj] = (jj == c) ? 2.f : 0.f;
#pragma unroll
            for (int i = 14; i >= 0; i--) {
                float s = 0.f;
#pragma unroll
                for (int j = i + 1; j < 16; j++)
                    s += Ts[(rb + i) * NVEC + rb + j] * xs[j];
                if (i < c) xs[i] = -2.f * s;
            }
        }
        __syncthreads();
        if (t < 128) {
#pragma unroll
            for (int i = 0; i < 16; i++)
                if (i <= c) Ts[(rb + i) * NVEC + rb + c] = xs[i];
        }
        __syncthreads();
    }

    // phase 2: combine levels
#pragma unroll
    for (int L = 16; L <= 64; L <<= 1) {
        int tpp = L << 2;
        int p   = t / tpp;
        int rem = t % tpp;
        int r   = rem / (L >> 2);
        int c0  = (rem % (L >> 2)) << 2;
        int a0  = p * (L << 1), b0 = a0 + L;
        int npanel = L >> 4;
        for (int pi = 0; pi < npanel; pi++) {
            int gr = a0 + pi * 16 + r;
            f32x4 acc = {0.f, 0.f, 0.f, 0.f};
            for (int k = pi * 16 + r; k < L; k++)
                acc += Ts[gr * NVEC + a0 + k] *
                       *(const f32x4*)&Ts[(a0 + k) * NVEC + b0 + c0];
            *(f32x4*)&Ts[(64 + r) * NVEC + p * L + c0] = acc;
            __syncthreads();
            f32x4 acc2 = {0.f, 0.f, 0.f, 0.f};
            for (int k = 0; k <= c0 + 3; k++)
                acc2 += Ts[(64 + r) * NVEC + p * L + k] *
                        *(const f32x4*)&Ts[(b0 + k) * NVEC + b0 + c0];
            *(f32x4*)&Ts[gr * NVEC + b0 + c0] = -acc2;
            __syncthreads();
        }
    }

    for (int idx = t; idx < NVEC * NVEC; idx += 256) {
        int i = idx >> 7, j = idx & 127;
        Tout[idx] = (j >= i) ? Ts[idx] : 0.f;
    }
}

// ---------------------------------------------------------------------------
// K3: WfT[i][d] = W[d][i] = sum_j Vn[d][j] * T[i][j]  (fp32, transposed store)
// ---------------------------------------------------------------------------
__global__ __launch_bounds__(256) void k_wmat(const float* __restrict__ VnT,
                                              const float* __restrict__ T,
                                              float* __restrict__ WfT) {
    __shared__ float Tl[NVEC * 130];
    int t = threadIdx.x;
#pragma unroll
    for (int m = 0; m < 32; ++m) {
        int idx = t * 2 + m * 512;
        float2 f = *(const float2*)(T + idx);
        int r = idx >> 7, c = idx & 127;
        *(float2*)&Tl[r * 130 + c] = f;
    }
    __syncthreads();
    int dl = t & 7, ig = t >> 3;
    int d  = blockIdx.x * 8 + dl;
    int i0 = ig * 4;
    float a0 = 0.f, a1 = 0.f, a2 = 0.f, a3 = 0.f;
#pragma unroll 4
    for (int j = 0; j < NVEC; ++j) {
        float vn = VnT[(size_t)j * DIM + d];
        a0 += vn * Tl[(i0 + 0) * 130 + j];
        a1 += vn * Tl[(i0 + 1) * 130 + j];
        a2 += vn * Tl[(i0 + 2) * 130 + j];
        a3 += vn * Tl[(i0 + 3) * 130 + j];
    }
    WfT[(size_t)(i0 + 0) * DIM + d] = a0;
    WfT[(size_t)(i0 + 1) * DIM + d] = a1;
    WfT[(size_t)(i0 + 2) * DIM + d] = a2;
    WfT[(size_t)(i0 + 3) * DIM + d] = a3;
}

// ---------------------------------------------------------------------------
// K4: Ct[c][d] = -sum_i WfT[i][c] * VnT[i][d]   (fp32 accumulate, bf16 store)
// out = x + x @ Ct^T + b collapses the two-GEMM cascade into one GEMM.
// Block = 64c x 64d tile, K=128. LDS broadcast reads (same-addr = free).
// ---------------------------------------------------------------------------
__global__ __launch_bounds__(256) void k_cmat(const float* __restrict__ VnT,
                                              const float* __restrict__ WfT,
                                              unsigned short* __restrict__ Ct16) {
    __shared__ float Ws[NVEC * 64];
    __shared__ float Vs[NVEC * 64];
    int t = threadIdx.x;
    int c0 = blockIdx.y * 64, d0 = blockIdx.x * 64;
    {   // stage: thread t -> row i = t>>1, half = t&1 (8 float4 each array)
        int i = t >> 1, hf = (t & 1) * 32;
        const float4* wsrc = (const float4*)(WfT + (size_t)i * DIM + c0 + hf);
        const float4* vsrc = (const float4*)(VnT + (size_t)i * DIM + d0 + hf);
#pragma unroll
        for (int j = 0; j < 8; ++j) {
            *(float4*)&Ws[i * 64 + hf + j * 4] = wsrc[j];
            *(float4*)&Vs[i * 64 + hf + j * 4] = vsrc[j];
        }
    }
    __syncthreads();
    int cl = t >> 4, dl = t & 15;
    f32x4 acc[4];
#pragma unroll
    for (int a = 0; a < 4; ++a) acc[a] = (f32x4){0.f, 0.f, 0.f, 0.f};
#pragma unroll 4
    for (int i = 0; i < NVEC; ++i) {
        f32x4 wv = *(const f32x4*)&Ws[i * 64 + cl * 4];
        f32x4 vv = *(const f32x4*)&Vs[i * 64 + dl * 4];
#pragma unroll
        for (int a = 0; a < 4; ++a) acc[a] += wv[a] * vv;
    }
#pragma unroll
    for (int a = 0; a < 4; ++a) {
        ushort4 h;
        h.x = f2bf(-acc[a][0]); h.y = f2bf(-acc[a][1]);
        h.z = f2bf(-acc[a][2]); h.w = f2bf(-acc[a][3]);
        *(ushort4*)(Ct16 + (size_t)(c0 + cl * 4 + a) * DIM + d0 + dl * 4) = h;
    }
}

// ---------------------------------------------------------------------------
// K5 (main): out = x + x @ Ct^T + b.  Single GEMM M=32768 N=1024 K=1024.
// 2048 blocks x 256 thr (4 waves 2x2, wave tile 64x64), 128^2 tile, BK=64,
// 16 K-steps, round-3 rhythm: stage -> barrier -> LDX(s+1) ahead -> MFMA.
// n_tile = bid&7: each XCD's blocks share one 256KB Ct panel (L2-resident).
// A: x reg-staged fp32->bf16, swizzled ds_write. B: Ct via cp16, pre-swizzled
// source (involution chunk^(row&7)). LDS 32KB -> 3 blocks/CU (launch_bounds
// (256,3), VGPR cap ~168: acc 64 + xf 32 + frags fits, no spill).
// Epilogue x re-read is L3-served. Ct panel L2 re-reads don't hit HBM.
// ---------------------------------------------------------------------------
__global__ __launch_bounds__(256, 3) void k_main(const float* __restrict__ x,
                                                 const unsigned short* __restrict__ Ct16,
                                                 const float* __restrict__ bias,
                                                 float* __restrict__ out) {
    __shared__ __align__(16) char smem[32768];
    char* Asb = smem;              // [128][128B] 16KB
    char* Bsb = smem + 16384;      // [128][128B] 16KB

    const int t   = threadIdx.x;
    const int bid = blockIdx.x;
    const int c0  = (bid & 7) * 128;        // n-tile == XCD (round-robin heuristic)
    const int r0  = (bid >> 3) * 128;       // m-tile
    const int w = t >> 6, l = t & 63, q = l >> 4, lm = l & 15;
    const int wrow = (w & 1) * 64, wcol = (w >> 1) * 64;
    const int ms = (lm & 7) << 4;

    // A staging map: thread -> row = t>>1, half = t&1 (32 cols = 8 float4)
    const int srow = t >> 1, shalf = t & 1;
    const float* xsrc = x + (size_t)(r0 + srow) * DIM + shalf * 32;
    char* aw = Asb + srow * 128;
    const int sswz = srow & 7;

    // B cp16 source: lane l -> row (l>>3), chunk-slot (l&7) holds logical
    // chunk (l&7)^(row&7); wave w covers rows w*32 + j*8.
    const unsigned short* bsrc0 = Ct16 + (size_t)(c0 + (l >> 3)) * DIM
                                + (((l & 7) ^ ((l >> 3) & 7)) << 3);

    float4 xf[8];

#define LDX(K0) { const float4* s4_ = (const float4*)(xsrc + (K0));             \
        _Pragma("unroll") for (int j_ = 0; j_ < 8; ++j_) xf[j_] = s4_[j_]; }

#define STX() { _Pragma("unroll") for (int j2_ = 0; j2_ < 4; ++j2_) {           \
        uint4 pk_;                                                              \
        pk_.x = (unsigned)f2bf(xf[2*j2_].x)   | ((unsigned)f2bf(xf[2*j2_].y)   << 16); \
        pk_.y = (unsigned)f2bf(xf[2*j2_].z)   | ((unsigned)f2bf(xf[2*j2_].w)   << 16); \
        pk_.z = (unsigned)f2bf(xf[2*j2_+1].x) | ((unsigned)f2bf(xf[2*j2_+1].y) << 16); \
        pk_.w = (unsigned)f2bf(xf[2*j2_+1].z) | ((unsigned)f2bf(xf[2*j2_+1].w) << 16); \
        *(uint4*)(aw + (((shalf * 4 + j2_) ^ sswz) << 4)) = pk_; } }

#define GLB(K0) { _Pragma("unroll") for (int j_ = 0; j_ < 4; ++j_) {            \
        cp16(bsrc0 + (size_t)(w * 32 + j_ * 8) * DIM + (K0),                    \
             Bsb + (w * 32 + j_ * 8) * 128); } }

    f32x4 acc[4][4];
#pragma unroll
    for (int mi = 0; mi < 4; ++mi)
#pragma unroll
        for (int nt = 0; nt < 4; ++nt) acc[mi][nt] = (f32x4){0.f, 0.f, 0.f, 0.f};

    LDX(0);
#pragma unroll 1
    for (int s = 0; s < 16; ++s) {
        __syncthreads();                 // prev-step MFMA reads of As/Bs done
        STX();                           // waits xf vmcnt; fp32->bf16; ds_write
        GLB(s * 64);                     // async Ct tile -> LDS (L2-resident)
        __syncthreads();                 // drain: both tiles ready
        if (s < 15) LDX((s + 1) * 64);   // next x tile flies during MFMA
#pragma unroll
        for (int kk = 0; kk < 64; kk += 32) {
            s16x8 af[4], bf[4];
            const int kb = (((kk + q * 8) * 2) ^ ms);
#pragma unroll
            for (int mi = 0; mi < 4; ++mi)
                af[mi] = *(const s16x8*)(Asb + (wrow + mi * 16 + lm) * 128 + kb);
#pragma unroll
            for (int nt = 0; nt < 4; ++nt)
                bf[nt] = *(const s16x8*)(Bsb + (wcol + nt * 16 + lm) * 128 + kb);
#pragma unroll
            for (int mi = 0; mi < 4; ++mi)
#pragma unroll
                for (int nt = 0; nt < 4; ++nt)
                    acc[mi][nt] = __builtin_amdgcn_mfma_f32_16x16x32_bf16(
                        af[mi], bf[nt], acc[mi][nt], 0, 0, 0);
        }
    }

    // epilogue: out = x + acc + b  (C/D layout col=lane&15, row=q*4+reg)
#pragma unroll
    for (int nt = 0; nt < 4; ++nt) {
        int col = c0 + wcol + nt * 16 + lm;
        float bv = bias[col];
#pragma unroll
        for (int mi = 0; mi < 4; ++mi) {
            int rowb = r0 + wrow + mi * 16 + q * 4;
#pragma unroll
            for (int rr = 0; rr < 4; ++rr) {
                size_t idx = (size_t)(rowb + rr) * DIM + col;
                out[idx] = x[idx] + acc[mi][nt][rr] + bv;
            }
        }
    }
#undef LDX
#undef STX
#undef GLB
}

// ---------------------------------------------------------------------------
extern "C" void kernel_launch(void* const* d_in, const int* in_sizes, int n_in,
                              void* d_out, int out_size, void* d_ws, size_t ws_size,
                              hipStream_t stream) {
    const float* x    = (const float*)d_in[0];
    const float* v    = (const float*)d_in[1];
    const float* bias = (const float*)d_in[2];
    float* out = (float*)d_out;

    char* ws = (char*)d_ws;
    float*          VnT  = (float*)(ws);                     // 512 KB [NVEC][DIM]
    float*          G0   = (float*)(ws + 524288);            // 64 KB  raw Gram
    float*          T    = (float*)(ws + 589824);            // 64 KB
    float*          rn   = (float*)(ws + 655360);            // 512 B
    float*          WfT  = (float*)(ws + 655872);            // 512 KB [NVEC][DIM]
    unsigned short* Ct16 = (unsigned short*)(ws + 1180160);  // 2 MB   [DIM][DIM] bf16

    k_normgram<<<NVEC, 256, 0, stream>>>(v, VnT, rn, G0);
    k_tinv<<<1, 256, 0, stream>>>(G0, rn, T);
    k_wmat<<<DIM / 8, 256, 0, stream>>>(VnT, T, WfT);
    k_cmat<<<dim3(DIM / 64, DIM / 64), 256, 0, stream>>>(VnT, WfT, Ct16);
    k_main<<<(BROWS / 128) * (DIM / 128), 256, 0, stream>>>(x, Ct16, bias, out);
}

// Round 8
// 338.873 us; speedup vs baseline: 1.3812x; 1.3812x over previous
//
#include <hip/hip_runtime.h>
#include <hip/hip_bf16.h>

#define DIM   1024
#define NVEC  128
#define BROWS 32768

typedef short s16x8 __attribute__((ext_vector_type(8)));
typedef float f32x4 __attribute__((ext_vector_type(4)));

__device__ __forceinline__ unsigned short f2bf(float f) {
    union { float f; unsigned int u; } c; c.f = f;
    unsigned int u = c.u;
    u += 0x7fffu + ((u >> 16) & 1u);   // round-to-nearest-even
    return (unsigned short)(u >> 16);
}

// async global->LDS, 16B per lane; LDS dest = wave-uniform base + lane*16
__device__ __forceinline__ void cp16(const void* g, void* l) {
    __builtin_amdgcn_global_load_lds(
        (const __attribute__((address_space(1))) unsigned int*)g,
        (__attribute__((address_space(3))) unsigned int*)l, 16, 0, 0);
}

// ---------------------------------------------------------------------------
// K1: per-column normalize v AND raw Gram row (rescale trick):
//   G[i][j] = <v_i_raw, v_j_raw> * rn_i * rn_j  (scaling applied in k_tinv)
// ---------------------------------------------------------------------------
__global__ __launch_bounds__(256) void k_normgram(const float* __restrict__ v,
                                                  float* __restrict__ VnT,
                                                  unsigned short* __restrict__ VnT16,
                                                  float* __restrict__ rn_out,
                                                  float* __restrict__ G0) {
    int i = blockIdx.x, t = threadIdx.x;
    __shared__ float col[DIM];
    __shared__ float red[4];
    __shared__ float part[256];
    float c4[4]; float ss = 0.f;
#pragma unroll
    for (int u = 0; u < 4; ++u) {
        int d = t + u * 256;
        float val = v[d * NVEC + i];
        c4[u] = val; col[d] = val; ss += val * val;
    }
#pragma unroll
    for (int o = 32; o > 0; o >>= 1) ss += __shfl_down(ss, o, 64);
    if ((t & 63) == 0) red[t >> 6] = ss;
    __syncthreads();
    float rn = rsqrtf(red[0] + red[1] + red[2] + red[3]);
    if (t == 0) rn_out[i] = rn;
#pragma unroll
    for (int u = 0; u < 4; ++u) {
        int d = t + u * 256;
        float val = c4[u] * rn;
        VnT[i * DIM + d]   = val;
        VnT16[i * DIM + d] = f2bf(val);
    }
    // raw Gram row: thread t -> j = t&127, d-half = t>>7 (lane-coalesced in j)
    int j = t & 127, half = t >> 7;
    const float* vp = v + (size_t)(half * 512) * NVEC + j;
    float s = 0.f;
#pragma unroll 4
    for (int d = 0; d < 512; ++d)
        s += col[half * 512 + d] * vp[(size_t)d * NVEC];
    part[t] = s;
    __syncthreads();
    if (t < 128) G0[i * NVEC + t] = part[t] + part[t + 128];
}

// ---------------------------------------------------------------------------
// K2: T = R^{-1}, R = 0.5*I + strict_upper(G), G = G0 * rn_i * rn_j
// ---------------------------------------------------------------------------
__global__ __launch_bounds__(256) void k_tinv(const float* __restrict__ G0,
                                              const float* __restrict__ rn,
                                              float* __restrict__ Tout) {
    __shared__ __align__(16) float Ts[NVEC * NVEC];   // 65536 B
    __shared__ float rs[NVEC];
    int t = threadIdx.x;
    if (t < NVEC) rs[t] = rn[t];
    __syncthreads();

    {   // phase 0: R into LDS (0.5 on diag, zeros below), rn rescale folded
        int i = t >> 1, jb = (t & 1) * 64;
        float rni = rs[i];
        for (int j = jb; j < jb + 64; j++) {
            float val = 0.f;
            if (j > i)       val = G0[i * NVEC + j] * rni * rs[j];
            else if (j == i) val = 0.5f;
            Ts[i * NVEC + j] = val;
        }
    }
    __syncthreads();

    {   // phase 1: invert 8 diagonal 16x16 blocks
        int blk = t >> 4, c = t & 15, rb = blk * 16;
        float xs[16];
        if (t < 128) {
#pragma unroll
            for (int jj = 0; jj < 16; jj++) xs[jj] = (jj == c) ? 2.f : 0.f;
#pragma unroll
            for (int i = 14; i >= 0; i--) {
                float s = 0.f;
#pragma unroll
                for (int j = i + 1; j < 16; j++)
                    s += Ts[(rb + i) * NVEC + rb + j] * xs[j];
                if (i < c) xs[i] = -2.f * s;
            }
        }
        __syncthreads();
        if (t < 128) {
#pragma unroll
            for (int i = 0; i < 16; i++)
                if (i <= c) Ts[(rb + i) * NVEC + rb + c] = xs[i];
        }
        __syncthreads();
    }

    // phase 2: combine levels
#pragma unroll
    for (int L = 16; L <= 64; L <<= 1) {
        int tpp = L << 2;
        int p   = t / tpp;
        int rem = t % tpp;
        int r   = rem / (L >> 2);
        int c0  = (rem % (L >> 2)) << 2;
        int a0  = p * (L << 1), b0 = a0 + L;
        int npanel = L >> 4;
        for (int pi = 0; pi < npanel; pi++) {
            int gr = a0 + pi * 16 + r;
            f32x4 acc = {0.f, 0.f, 0.f, 0.f};
            for (int k = pi * 16 + r; k < L; k++)
                acc += Ts[gr * NVEC + a0 + k] *
                       *(const f32x4*)&Ts[(a0 + k) * NVEC + b0 + c0];
            *(f32x4*)&Ts[(64 + r) * NVEC + p * L + c0] = acc;
            __syncthreads();
            f32x4 acc2 = {0.f, 0.f, 0.f, 0.f};
            for (int k = 0; k <= c0 + 3; k++)
                acc2 += Ts[(64 + r) * NVEC + p * L + k] *
                        *(const f32x4*)&Ts[(b0 + k) * NVEC + b0 + c0];
            *(f32x4*)&Ts[gr * NVEC + b0 + c0] = -acc2;
            __syncthreads();
        }
    }

    for (int idx = t; idx < NVEC * NVEC; idx += 256) {
        int i = idx >> 7, j = idx & 127;
        Tout[idx] = (j >= i) ? Ts[idx] : 0.f;
    }
}

// ---------------------------------------------------------------------------
// K3: W[d][i] = sum_j Vn[d][j] * T[i][j]   (T has explicit zeros below diag)
// ---------------------------------------------------------------------------
__global__ __launch_bounds__(256) void k_wmat(const float* __restrict__ VnT,
                                              const float* __restrict__ T,
                                              unsigned short* __restrict__ W16) {
    __shared__ float Tl[NVEC * 130];
    int t = threadIdx.x;
#pragma unroll
    for (int m = 0; m < 32; ++m) {
        int idx = t * 2 + m * 512;
        float2 f = *(const float2*)(T + idx);
        int r = idx >> 7, c = idx & 127;
        *(float2*)&Tl[r * 130 + c] = f;
    }
    __syncthreads();
    int dl = t & 7, ig = t >> 3;
    int d  = blockIdx.x * 8 + dl;
    int i0 = ig * 4;
    float a0 = 0.f, a1 = 0.f, a2 = 0.f, a3 = 0.f;
#pragma unroll 4
    for (int j = 0; j < NVEC; ++j) {
        float vn = VnT[(size_t)j * DIM + d];
        a0 += vn * Tl[(i0 + 0) * 130 + j];
        a1 += vn * Tl[(i0 + 1) * 130 + j];
        a2 += vn * Tl[(i0 + 2) * 130 + j];
        a3 += vn * Tl[(i0 + 3) * 130 + j];
    }
    ushort4 h; h.x = f2bf(a0); h.y = f2bf(a1); h.z = f2bf(a2); h.w = f2bf(a3);
    *(ushort4*)(W16 + (size_t)d * NVEC + i0) = h;
}

// ---------------------------------------------------------------------------
// K4 (fused cascade, 4 blocks/CU): 1024 blocks x 256 threads (4 waves).
// Round-7 lesson: the cascade (rank-128 Y bottleneck in LDS) is the minimum-
// traffic dataflow -- keep it. Round-3 limiter: 2 big blocks/CU = 2 barrier
// domains; every vmcnt(0) drain stalls half the CU. Fix: 32-row blocks,
// 40KB LDS -> 4 independent blocks/CU; a draining block is covered by the
// other three. Staging maps/swizzles/rhythm identical to round 3 (verified).
//   phase A: Y = x @ Vn, BK=128, 8 steps: x reg-staged (LDX s+1 ahead,
//            16 VGPR), Vn via cp16 pre-swizzled source. 2 barriers/step.
//   handoff: Y (bf16) -> LDS swizzled; ya hoisted to 16 VGPR.
//   phase B: out = x - Y @ W^T + b, 8 ct tiles, W via cp16. 2 barriers/ct.
// Wave tile 16x64: acc[4] = 16 VGPR. launch_bounds(256,4) caps VGPR at 128.
// LDS: phase A As[32][256B]=8K + Bs[128][256B]=32K; phase B Ys[32][256B]=8K
// + Ws[128][256B]=32K; aliased, 40KB total.
// ---------------------------------------------------------------------------
__global__ __launch_bounds__(256, 4) void k_fused(const float* __restrict__ x,
                                                  const unsigned short* __restrict__ VnT16,
                                                  const unsigned short* __restrict__ W16,
                                                  const float* __restrict__ bias,
                                                  float* __restrict__ out) {
    __shared__ __align__(16) char smem[40960];       // 40 KB
    char* Asb = smem;                                // [32][256B]   8KB (phase A)
    char* Bsb = smem + 8192;                         // [128][256B] 32KB (phase A)
    char* Ysb = smem;                                // [32][256B]   8KB (phase B)
    char* Wsb = smem + 8192;                         // [128][256B] 32KB (phase B)

    const int t  = threadIdx.x;
    const int r0 = blockIdx.x * 32;
    const int w  = t >> 6, l = t & 63, q = l >> 4, lm = l & 15;
    const int wm = w & 1, wn = w >> 1;               // wave tile: rows wm*16, cols wn*64
    const int ms = lm << 4;

    // A staging: thread -> row = t>>3 (0..31), seg = t&7 (16 floats each)
    const int srow = t >> 3, sseg = t & 7;
    const float* xsrc = x + (size_t)(r0 + srow) * DIM + sseg * 16;
    char* aw = Asb + srow * 256;
    const int sswz = srow & 15;

    float4 xf[4];

#define LDX(K0) { const float4* s4_ = (const float4*)(xsrc + (K0));             \
        xf[0] = s4_[0]; xf[1] = s4_[1]; xf[2] = s4_[2]; xf[3] = s4_[3]; }

    // 16 floats -> 2 swizzled 16B chunks (chunks 2*seg, 2*seg+1)
#define STX() { _Pragma("unroll") for (int j2_ = 0; j2_ < 2; ++j2_) {           \
        uint4 pk_;                                                              \
        pk_.x = (unsigned)f2bf(xf[2*j2_].x)   | ((unsigned)f2bf(xf[2*j2_].y)   << 16); \
        pk_.y = (unsigned)f2bf(xf[2*j2_].z)   | ((unsigned)f2bf(xf[2*j2_].w)   << 16); \
        pk_.z = (unsigned)f2bf(xf[2*j2_+1].x) | ((unsigned)f2bf(xf[2*j2_+1].y) << 16); \
        pk_.w = (unsigned)f2bf(xf[2*j2_+1].z) | ((unsigned)f2bf(xf[2*j2_+1].w) << 16); \
        *(uint4*)(aw + (((sseg * 2 + j2_) ^ sswz) << 4)) = pk_; } }

    // Vn tile: 128 rows x 256B; wave w stages rows w*32 + j*4 (+ l>>4)
#define GLB(K0) { _Pragma("unroll") for (int j_ = 0; j_ < 8; ++j_) {            \
        int row_ = w * 32 + j_ * 4 + (l >> 4);                                  \
        cp16(VnT16 + (size_t)row_ * DIM + (K0) + (((l & 15) ^ (row_ & 15)) << 3), \
             Bsb + (w * 32 + j_ * 4) * 256); } }

#define GLW(CT) { _Pragma("unroll") for (int j_ = 0; j_ < 8; ++j_) {            \
        int row_ = w * 32 + j_ * 4 + (l >> 4);                                  \
        cp16(W16 + (size_t)((CT) * 128 + row_) * NVEC + (((l & 15) ^ (row_ & 15)) << 3), \
             Wsb + (w * 32 + j_ * 4) * 256); } }

    // ---------------- phase A: Y = x @ Vn ----------------
    f32x4 acc[4];
#pragma unroll
    for (int n = 0; n < 4; ++n) acc[n] = (f32x4){0.f, 0.f, 0.f, 0.f};

    LDX(0);
#pragma unroll 1
    for (int s = 0; s < 8; ++s) {
        __syncthreads();                 // prev-step MFMA reads of As/Bs done
        STX();                           // waits xf vmcnt; fp32->bf16; ds_write
        GLB(s * 128);                    // async Vn tile -> LDS (L2-resident)
        __syncthreads();                 // drain: both tiles ready
        if (s < 7) LDX((s + 1) * 128);   // next x tile flies during MFMA
#pragma unroll
        for (int kk = 0; kk < 128; kk += 32) {
            const int kb = (((kk + q * 8) * 2) ^ ms);
            s16x8 a = *(const s16x8*)(Asb + (wm * 16 + lm) * 256 + kb);
#pragma unroll
            for (int nt = 0; nt < 4; ++nt) {
                s16x8 b = *(const s16x8*)(Bsb + (wn * 64 + nt * 16 + lm) * 256 + kb);
                acc[nt] = __builtin_amdgcn_mfma_f32_16x16x32_bf16(a, b, acc[nt], 0, 0, 0);
            }
        }
    }

    __syncthreads();                     // all phase-A LDS reads done

    // Y (bf16) -> LDS, swizzled. C/D layout: col=lane&15, row=q*4+reg.
    {
        int yr0 = wm * 16 + q * 4;
#pragma unroll
        for (int nt = 0; nt < 4; ++nt) {
            int col2 = (wn * 64 + nt * 16 + lm) * 2;
#pragma unroll
            for (int r = 0; r < 4; ++r) {
                int row = yr0 + r;
                *(unsigned short*)(Ysb + row * 256 + (col2 ^ ((row & 15) << 4)))
                    = f2bf(acc[nt][r]);
            }
        }
    }
    __syncthreads();                     // Ys visible everywhere

    // ---------------- phase B: out = x - Y @ W^T + b ----------------
    // Y A-frags are ct-invariant: hoist to 16 VGPR.
    const int arow = (wm * 16 + lm) * 256;
    s16x8 ya[4];
#pragma unroll
    for (int kk = 0; kk < 4; ++kk)
        ya[kk] = *(const s16x8*)(Ysb + arow + (((kk * 32 + q * 8) * 2) ^ ms));

    const int orow = r0 + wm * 16 + q * 4;

#pragma unroll 1
    for (int ct = 0; ct < 8; ++ct) {
        if (ct > 0) __syncthreads();     // prev Ws reads done
        GLW(ct);                         // async W tile -> LDS (L2-resident)
        __syncthreads();                 // tile ready

        f32x4 oacc[4];
#pragma unroll
        for (int n = 0; n < 4; ++n) oacc[n] = (f32x4){0.f, 0.f, 0.f, 0.f};
#pragma unroll
        for (int kk = 0; kk < 4; ++kk) {
            const int kb = (((kk * 32 + q * 8) * 2) ^ ms);
#pragma unroll
            for (int nt = 0; nt < 4; ++nt) {
                s16x8 b = *(const s16x8*)(Wsb + (wn * 64 + nt * 16 + lm) * 256 + kb);
                oacc[nt] = __builtin_amdgcn_mfma_f32_16x16x32_bf16(ya[kk], b, oacc[nt], 0, 0, 0);
            }
        }

        // epilogue: out = x - acc + b (x re-read is L2/L3-served)
#pragma unroll
        for (int nt = 0; nt < 4; ++nt) {
            int col = ct * 128 + wn * 64 + nt * 16 + lm;
            float bv = bias[col];
#pragma unroll
            for (int r = 0; r < 4; ++r) {
                size_t idx = (size_t)(orow + r) * DIM + col;
                out[idx] = x[idx] - oacc[nt][r] + bv;
            }
        }
    }
#undef LDX
#undef STX
#undef GLB
#undef GLW
}

// ---------------------------------------------------------------------------
extern "C" void kernel_launch(void* const* d_in, const int* in_sizes, int n_in,
                              void* d_out, int out_size, void* d_ws, size_t ws_size,
                              hipStream_t stream) {
    const float* x    = (const float*)d_in[0];
    const float* v    = (const float*)d_in[1];
    const float* bias = (const float*)d_in[2];
    float* out = (float*)d_out;

    char* ws = (char*)d_ws;
    float*          VnT   = (float*)(ws);                    // 512 KB  [NVEC][DIM] fp32
    unsigned short* VnT16 = (unsigned short*)(ws + 524288);  // 256 KB  [NVEC][DIM] bf16
    float*          G0    = (float*)(ws + 786432);           // 64 KB   raw Gram
    float*          T     = (float*)(ws + 851968);           // 64 KB
    float*          rn    = (float*)(ws + 917504);           // 512 B   col inv-norms
    unsigned short* W16   = (unsigned short*)(ws + 921600);  // 256 KB  [DIM][NVEC] bf16

    k_normgram<<<NVEC, 256, 0, stream>>>(v, VnT, VnT16, rn, G0);
    k_tinv<<<1, 256, 0, stream>>>(G0, rn, T);
    k_wmat<<<DIM / 8, 256, 0, stream>>>(VnT, T, W16);
    k_fused<<<BROWS / 32, 256, 0, stream>>>(x, VnT16, W16, bias, out);
}